// Round 5
// baseline (483.521 us; speedup 1.0000x reference)
//
#include <hip/hip_runtime.h>

#define N_NODES   50000
#define N_EDGES   800000
#define HID       64
#define NUM_GRAPHS 50
#define EPS       1e-5f
#define NB_COMBINE 256
#define NHPAD     50176          // 98 * 512, padded histogram/scan size
#define SCAN_B    98

typedef __attribute__((ext_vector_type(8))) short short8;
typedef __attribute__((ext_vector_type(4))) float f32x4;

__device__ __forceinline__ unsigned short bfbits(float x) {
    __bf16 h = (__bf16)x;
    return __builtin_bit_cast(unsigned short, h);
}
__device__ __forceinline__ float bffloat(unsigned short b) {
    return __builtin_bit_cast(float, (unsigned int)b << 16);
}
// 8 fp32 -> bf16 hi/lo fragments
__device__ __forceinline__ void cvt8(const float4& a, const float4& b,
                                     short8& hi, short8& lo) {
    float f[8] = {a.x, a.y, a.z, a.w, b.x, b.y, b.z, b.w};
#pragma unroll
    for (int i = 0; i < 8; ++i) {
        unsigned short hb = bfbits(f[i]);
        hi[i] = (short)hb;
        lo[i] = (short)bfbits(f[i] - bffloat(hb));
    }
}

// ---------------------------------------------------------------------------
// Int histogram of dst (degree count).
__global__ __launch_bounds__(256) void k_hist(const int* __restrict__ dst,
                                              int* __restrict__ ihist) {
    int tid = blockIdx.x * blockDim.x + threadIdx.x;
    int stride = gridDim.x * blockDim.x;
    for (int e = tid; e < N_EDGES; e += stride) atomicAdd(&ihist[dst[e]], 1);
}

// Exclusive scan, pass 1: per-block (512 elems) local scan + block sums.
__global__ __launch_bounds__(512) void k_scan1(const int* __restrict__ ihist,
                                               int* __restrict__ off,
                                               int* __restrict__ bsum) {
    __shared__ int s[512];
    const int t = threadIdx.x, i = blockIdx.x * 512 + t;
    const int v = ihist[i];
    s[t] = v;
    __syncthreads();
    for (int o = 1; o < 512; o <<= 1) {
        int u = (t >= o) ? s[t - o] : 0;
        __syncthreads();
        s[t] += u;
        __syncthreads();
    }
    off[i] = s[t] - v;
    if (t == 511) bsum[blockIdx.x] = s[t];
}

// pass 2: serial exclusive scan of the 98 block sums.
__global__ void k_scan2(const int* __restrict__ bsum, int* __restrict__ bscan) {
    if (threadIdx.x == 0) {
        int acc = 0;
        for (int b = 0; b < SCAN_B; ++b) { bscan[b] = acc; acc += bsum[b]; }
    }
}

// pass 3: add block offsets; duplicate into mutable cursor for the scatter.
__global__ __launch_bounds__(512) void k_scan3(int* __restrict__ off,
                                               const int* __restrict__ bscan,
                                               int* __restrict__ off_cur) {
    const int i = blockIdx.x * 512 + threadIdx.x;
    const int v = off[i] + bscan[i >> 9];
    off[i] = v;
    off_cur[i] = v;
}

// Counting-sort scatter: edge arrays reordered by dst.
__global__ __launch_bounds__(256) void k_scatter(const int* __restrict__ src,
                                                 const int* __restrict__ dst,
                                                 int* __restrict__ off_cur,
                                                 int* __restrict__ ssrc,
                                                 int* __restrict__ sdsts,
                                                 int* __restrict__ seid) {
    int tid = blockIdx.x * blockDim.x + threadIdx.x;
    int stride = gridDim.x * blockDim.x;
    for (int e = tid; e < N_EDGES; e += stride) {
        const int d = dst[e];
        const int p = atomicAdd(&off_cur[d], 1);
        ssrc[p] = src[e];
        sdsts[p] = d;
        seid[p] = e;
    }
}

// ---------------------------------------------------------------------------
__global__ void k_gcnt(const int* __restrict__ batch, float* __restrict__ gcnt) {
    int g = threadIdx.x;
    if (g >= NUM_GRAPHS) return;
    auto lb = [&](int val) {
        int lo = 0, hi = N_NODES;
        while (lo < hi) { int mid = (lo + hi) >> 1; if (batch[mid] < val) lo = mid + 1; else hi = mid; }
        return lo;
    };
    gcnt[g] = (float)(lb(g + 1) - lb(g));
}

// ---------------------------------------------------------------------------
// Weight prep: W[96][64] fp32 -> Wt hi/lo [64][104] bf16 (transposed, padded).
__global__ void k_prepW(const float* __restrict__ W, unsigned short* __restrict__ Whi,
                        unsigned short* __restrict__ Wlo) {
    int t = blockIdx.x * blockDim.x + threadIdx.x;
    if (t >= 96 * 64) return;
    int k = t >> 6, n = t & 63;
    float x = W[t];
    unsigned short hb = bfbits(x);
    float lof = x - bffloat(hb);
    Whi[n * 104 + k] = hb;
    Wlo[n * 104 + k] = bfbits(lof);
}

// ---------------------------------------------------------------------------
// x[N,64] fp32 -> packed bf16 hi/lo arrays (same row-major layout).
__global__ __launch_bounds__(256) void k_prepX(const float* __restrict__ x,
                                               unsigned short* __restrict__ xhi,
                                               unsigned short* __restrict__ xlo) {
    int t = blockIdx.x * blockDim.x + threadIdx.x;
    if (t >= N_NODES * 8) return;
    const float* r = x + (size_t)t * 8;
    float4 a = ((const float4*)r)[0];
    float4 b = ((const float4*)r)[1];
    short8 hi, lo;
    cvt8(a, b, hi, lo);
    *(short8*)(xhi + (size_t)t * 8) = hi;
    *(short8*)(xlo + (size_t)t * 8) = lo;
}

// ---------------------------------------------------------------------------
// Fused BN-apply (layer1) + layer-2 operand prep:
// hn = relu(h*sc+sh) fp32  AND  hhi/hlo bf16 split.
__global__ __launch_bounds__(256) void k_prepH(const float* __restrict__ h,
                                               const float* __restrict__ ss,
                                               float* __restrict__ hn,
                                               unsigned short* __restrict__ hhi,
                                               unsigned short* __restrict__ hlo) {
    int t = blockIdx.x * blockDim.x + threadIdx.x;
    if (t >= N_NODES * 8) return;
    const int f0 = (t & 7) * 8;
    float4 sca = *(const float4*)(ss + f0);
    float4 scb = *(const float4*)(ss + f0 + 4);
    float4 sha = *(const float4*)(ss + 64 + f0);
    float4 shb = *(const float4*)(ss + 64 + f0 + 4);
    const float* r = h + (size_t)t * 8;
    float4 a = ((const float4*)r)[0];
    float4 b = ((const float4*)r)[1];
    a.x = fmaxf(a.x * sca.x + sha.x, 0.f);
    a.y = fmaxf(a.y * sca.y + sha.y, 0.f);
    a.z = fmaxf(a.z * sca.z + sha.z, 0.f);
    a.w = fmaxf(a.w * sca.w + sha.w, 0.f);
    b.x = fmaxf(b.x * scb.x + shb.x, 0.f);
    b.y = fmaxf(b.y * scb.y + shb.y, 0.f);
    b.z = fmaxf(b.z * scb.z + shb.z, 0.f);
    b.w = fmaxf(b.w * scb.w + shb.w, 0.f);
    ((float4*)(hn + (size_t)t * 8))[0] = a;
    ((float4*)(hn + (size_t)t * 8))[1] = b;
    short8 hi, lo;
    cvt8(a, b, hi, lo);
    *(short8*)(hhi + (size_t)t * 8) = hi;
    *(short8*)(hlo + (size_t)t * 8) = lo;
}

// ---------------------------------------------------------------------------
// Edge message via MFMA over 64 dst-sorted edges per block.
// A-fragments gathered DIRECTLY from global (prepacked bf16 x; fp32 ea
// converted in-register). No A-staging LDS, single barrier before the
// segment-reduce epilogue.
__global__ __launch_bounds__(256) void k_edge(const unsigned short* __restrict__ xhi, // [N][64]
                                              const unsigned short* __restrict__ xlo,
                                              const float* __restrict__ ea,    // [E,32]
                                              const int*   __restrict__ ssrc,
                                              const int*   __restrict__ sdsts,
                                              const int*   __restrict__ seid,
                                              const unsigned short* __restrict__ Whi, // [64][104]
                                              const unsigned short* __restrict__ Wlo,
                                              const float* __restrict__ bias,
                                              float* __restrict__ aggr) {      // [N,64]
    __shared__ float msg[64 * 68];
    __shared__ int ldst[64];

    const int tid  = threadIdx.x;
    const int lane = tid & 63;
    const int w    = tid >> 6;
    const int e0   = blockIdx.x * 64;

    const int fr    = lane & 15;
    const int koff  = (lane >> 4) * 8;
    const int nbase = (w & 1) * 32;
    const int mbase = (w >> 1) * 32;

    if (tid < 64) ldst[tid] = sdsts[e0 + tid];

    // this lane's two edge rows (m=0, m=1 tiles)
    const int r0 = mbase + fr;
    const int r1 = r0 + 16;
    const int s0  = ssrc[e0 + r0];
    const int s1  = ssrc[e0 + r1];
    const int id0 = seid[e0 + r0];
    const int id1 = seid[e0 + r1];

    // B fragments resident: 2 N-tiles x 3 K-blocks x {hi,lo}
    short8 bh[2][3], bl[2][3];
#pragma unroll
    for (int n = 0; n < 2; ++n)
#pragma unroll
        for (int kb = 0; kb < 3; ++kb) {
            const int row = nbase + n * 16 + fr;
            bh[n][kb] = *(const short8*)(Whi + row * 104 + kb * 32 + koff);
            bl[n][kb] = *(const short8*)(Wlo + row * 104 + kb * 32 + koff);
        }

    // A fragments: x-part (kb=0,1) direct bf16 gather
    short8 ah[2][3], al[2][3];
    ah[0][0] = *(const short8*)(xhi + (size_t)s0 * 64 + koff);
    ah[0][1] = *(const short8*)(xhi + (size_t)s0 * 64 + 32 + koff);
    ah[1][0] = *(const short8*)(xhi + (size_t)s1 * 64 + koff);
    ah[1][1] = *(const short8*)(xhi + (size_t)s1 * 64 + 32 + koff);
    al[0][0] = *(const short8*)(xlo + (size_t)s0 * 64 + koff);
    al[0][1] = *(const short8*)(xlo + (size_t)s0 * 64 + 32 + koff);
    al[1][0] = *(const short8*)(xlo + (size_t)s1 * 64 + koff);
    al[1][1] = *(const short8*)(xlo + (size_t)s1 * 64 + 32 + koff);
    // ea-part (kb=2): fp32 load + in-register hi/lo split
    {
        float4 a0 = *(const float4*)(ea + (size_t)id0 * 32 + koff);
        float4 b0 = *(const float4*)(ea + (size_t)id0 * 32 + koff + 4);
        float4 a1 = *(const float4*)(ea + (size_t)id1 * 32 + koff);
        float4 b1 = *(const float4*)(ea + (size_t)id1 * 32 + koff + 4);
        cvt8(a0, b0, ah[0][2], al[0][2]);
        cvt8(a1, b1, ah[1][2], al[1][2]);
    }

    f32x4 acc[2][2] = {};
#pragma unroll
    for (int kb = 0; kb < 3; ++kb)
#pragma unroll
        for (int m = 0; m < 2; ++m)
#pragma unroll
            for (int n = 0; n < 2; ++n) {
                acc[m][n] = __builtin_amdgcn_mfma_f32_16x16x32_bf16(ah[m][kb], bh[n][kb], acc[m][n], 0, 0, 0);
                acc[m][n] = __builtin_amdgcn_mfma_f32_16x16x32_bf16(al[m][kb], bh[n][kb], acc[m][n], 0, 0, 0);
                acc[m][n] = __builtin_amdgcn_mfma_f32_16x16x32_bf16(ah[m][kb], bl[n][kb], acc[m][n], 0, 0, 0);
            }

    // bias + ReLU, store per-edge messages (C layout: col=lane&15, row=(lane>>4)*4+j)
    const float bv0 = bias[nbase + fr];
    const float bv1 = bias[nbase + 16 + fr];
    const int rb = (lane >> 4) * 4;
#pragma unroll
    for (int m = 0; m < 2; ++m)
#pragma unroll
        for (int j = 0; j < 4; ++j) {
            const int r = mbase + m * 16 + rb + j;
            msg[r * 68 + nbase + fr]      = fmaxf(acc[m][0][j] + bv0, 0.f);
            msg[r * 68 + nbase + 16 + fr] = fmaxf(acc[m][1][j] + bv1, 0.f);
        }
    __syncthreads();

    // strip segment-reduce: wave w owns rows [16w,16w+16), lane owns feature f.
    {
        const int f = lane;
        const int r0s = w * 16;
        int cur = ldst[r0s];
        float a2 = 0.f;
        for (int r = r0s; r < r0s + 16; ++r) {
            const int d = ldst[r];  // wave-uniform broadcast
            if (d != cur) {
                unsafeAtomicAdd(&aggr[(size_t)cur * 64 + f], a2);
                a2 = 0.f;
                cur = d;
            }
            a2 += msg[r * 68 + f];
        }
        unsafeAtomicAdd(&aggr[(size_t)cur * 64 + f], a2);
    }
}

// ---------------------------------------------------------------------------
// h = xin @ Wr + aggr/max(deg,1); per-block BN partial sums (no atomics).
__global__ __launch_bounds__(256) void k_combine(const float* __restrict__ xin,  // [N,64]
                                                 const float* __restrict__ Wr,   // [64,64]
                                                 const float* __restrict__ aggr, // [N,64]
                                                 const int*   __restrict__ ihist,// [N]
                                                 float* __restrict__ h,          // [N,64]
                                                 float* __restrict__ partial) {  // [NB,128]
    const int lane = threadIdx.x & 63;
    const int wv   = threadIdx.x >> 6;
    const int wid  = (blockIdx.x * blockDim.x + threadIdx.x) >> 6;
    const int nw   = (gridDim.x * blockDim.x) >> 6;

    float w[64];
#pragma unroll
    for (int k = 0; k < 64; ++k) w[k] = Wr[k * 64 + lane];

    float rs = 0.f, rq = 0.f;
    for (int n = wid; n < N_NODES; n += nw) {
        const float* __restrict__ xr = xin + (size_t)n * 64;
        const float c = fmaxf((float)ihist[n], 1.0f);  // uniform
        float acc = aggr[(size_t)n * 64 + lane] / c;
#pragma unroll
        for (int k = 0; k < 64; ++k) acc += xr[k] * w[k];
        h[(size_t)n * 64 + lane] = acc;
        rs += acc;
        rq += acc * acc;
    }
    __shared__ float ssum[4][64];
    __shared__ float ssq[4][64];
    ssum[wv][lane] = rs;
    ssq[wv][lane]  = rq;
    __syncthreads();
    if (threadIdx.x < 64) {
        float s = ssum[0][lane] + ssum[1][lane] + ssum[2][lane] + ssum[3][lane];
        partial[blockIdx.x * 128 + lane] = s;
    } else if (threadIdx.x < 128) {
        int l = threadIdx.x - 64;
        float q = ssq[0][l] + ssq[1][l] + ssq[2][l] + ssq[3][l];
        partial[blockIdx.x * 128 + 64 + l] = q;
    }
}

// ---------------------------------------------------------------------------
__global__ void k_bnfin(const float* __restrict__ partial, const float* __restrict__ g,
                        const float* __restrict__ be, float* __restrict__ ss) {
    __shared__ float tot[128];
    int t = threadIdx.x;
    float s = 0.f;
    for (int b = 0; b < NB_COMBINE; ++b) s += partial[b * 128 + t];
    tot[t] = s;
    __syncthreads();
    if (t < 64) {
        float mu  = tot[t] * (1.0f / (float)N_NODES);
        float var = tot[64 + t] * (1.0f / (float)N_NODES) - mu * mu;
        float sc  = g[t] * rsqrtf(var + EPS);
        ss[t]      = sc;
        ss[64 + t] = be[t] - mu * sc;
    }
}

// ---------------------------------------------------------------------------
// Fused BN-apply (layer2) + global mean pool partial sums (sorted-run atomics).
__global__ __launch_bounds__(256) void k_bnpool(const float* __restrict__ h,
                                                const float* __restrict__ ss,
                                                const int* __restrict__ batch,
                                                float* __restrict__ gsum) {
    const int lane = threadIdx.x & 63;
    const int wid  = (blockIdx.x * blockDim.x + threadIdx.x) >> 6;
    const int nw   = (gridDim.x * blockDim.x) >> 6;
    const float sc = ss[lane];
    const float sh = ss[64 + lane];
    const int chunk = (N_NODES + nw - 1) / nw;
    const int n0 = wid * chunk;
    const int n1 = min(n0 + chunk, N_NODES);
    int curg = -1;
    float acc = 0.f;
    for (int n = n0; n < n1; ++n) {
        int g = __builtin_amdgcn_readfirstlane(batch[n]);
        if (g != curg) {
            if (curg >= 0) unsafeAtomicAdd(&gsum[curg * 64 + lane], acc);
            curg = g;
            acc = 0.f;
        }
        acc += fmaxf(h[(size_t)n * 64 + lane] * sc + sh, 0.f);
    }
    if (curg >= 0) unsafeAtomicAdd(&gsum[curg * 64 + lane], acc);
}

// ---------------------------------------------------------------------------
__global__ void k_final(const float* __restrict__ gsum, const float* __restrict__ gcnt,
                        const float* __restrict__ Wro, const float* __restrict__ bro,
                        float* __restrict__ out) {
    int g = blockIdx.x;
    int lane = threadIdx.x;
    float v = gsum[g * 64 + lane] / fmaxf(gcnt[g], 1.0f) * Wro[lane];
#pragma unroll
    for (int off = 32; off > 0; off >>= 1) v += __shfl_down(v, off, 64);
    if (lane == 0) out[g] = v + bro[0];
}

// ---------------------------------------------------------------------------
extern "C" void kernel_launch(void* const* d_in, const int* in_sizes, int n_in,
                              void* d_out, int out_size, void* d_ws, size_t ws_size,
                              hipStream_t stream) {
    (void)in_sizes; (void)n_in; (void)out_size; (void)ws_size;
    const float* x    = (const float*)d_in[0];
    const int*   ei   = (const int*)d_in[1];   // [2, E]
    const float* ea   = (const float*)d_in[2];
    const int*   batch= (const int*)d_in[3];
    const float* Wn1  = (const float*)d_in[4];
    const float* bn1  = (const float*)d_in[5];
    const float* Wr1  = (const float*)d_in[6];
    const float* g1   = (const float*)d_in[7];
    const float* be1  = (const float*)d_in[8];
    const float* Wn2  = (const float*)d_in[9];
    const float* bn2  = (const float*)d_in[10];
    const float* Wr2  = (const float*)d_in[11];
    const float* g2   = (const float*)d_in[12];
    const float* be2  = (const float*)d_in[13];
    const float* Wro  = (const float*)d_in[14];
    const float* bro  = (const float*)d_in[15];
    const int* src = ei;
    const int* dst = ei + N_EDGES;

    float* ws = (float*)d_ws;
    // ---- zeroed region: [gsum | aggr | ihist] ----
    float* gsum   = ws;                               // 3200
    float* aggr   = gsum + 3200;                      // N*64
    int*   ihist  = (int*)(aggr + (size_t)N_NODES * 64); // NHPAD
    const size_t zero_floats = 3200 + (size_t)N_NODES * 64 + NHPAD;
    // ---- non-zeroed ----
    float* h      = (float*)(ihist + NHPAD);
    float* hn     = h + (size_t)N_NODES * 64;
    float* gcnt   = hn + (size_t)N_NODES * 64;        // 64
    float* part1  = gcnt + 64;                        // NB*128
    float* part2  = part1 + NB_COMBINE * 128;
    float* ss1    = part2 + NB_COMBINE * 128;         // 128
    float* ss2    = ss1 + 128;                        // 128
    unsigned short* wb = (unsigned short*)(ss2 + 128);
    unsigned short* Wh1 = wb;                         // 64*104 each
    unsigned short* Wl1 = wb + 6656;
    unsigned short* Wh2 = wb + 13312;
    unsigned short* Wl2 = wb + 19968;
    int* off     = (int*)(wb + 26624);                // NHPAD
    int* off_cur = off + NHPAD;                       // NHPAD
    int* bsum    = off_cur + NHPAD;                   // 128
    int* bscan   = bsum + 128;                        // 128
    int* ssrc    = bscan + 128;                       // E
    int* sdsts   = ssrc + N_EDGES;                    // E
    int* seid    = sdsts + N_EDGES;                   // E
    unsigned short* xhi = (unsigned short*)(seid + N_EDGES); // N*64 each
    unsigned short* xlo = xhi + (size_t)N_NODES * 64;
    unsigned short* hhi = xlo + (size_t)N_NODES * 64;
    unsigned short* hlo = hhi + (size_t)N_NODES * 64;

    hipMemsetAsync(d_ws, 0, zero_floats * sizeof(float), stream);

    // ---- edge sort by dst (shared by both layers) ----
    k_hist<<<512, 256, 0, stream>>>(dst, ihist);
    k_scan1<<<SCAN_B, 512, 0, stream>>>(ihist, off, bsum);
    k_scan2<<<1, 64, 0, stream>>>(bsum, bscan);
    k_scan3<<<SCAN_B, 512, 0, stream>>>(off, bscan, off_cur);
    k_scatter<<<512, 256, 0, stream>>>(src, dst, off_cur, ssrc, sdsts, seid);

    k_gcnt<<<1, 64, 0, stream>>>(batch, gcnt);
    k_prepW<<<24, 256, 0, stream>>>(Wn1, Wh1, Wl1);
    k_prepW<<<24, 256, 0, stream>>>(Wn2, Wh2, Wl2);
    k_prepX<<<(N_NODES * 8 + 255) / 256, 256, 0, stream>>>(x, xhi, xlo);

    // ---- layer 1 ----
    k_edge<<<N_EDGES / 64, 256, 0, stream>>>(xhi, xlo, ea, ssrc, sdsts, seid, Wh1, Wl1, bn1, aggr);
    k_combine<<<NB_COMBINE, 256, 0, stream>>>(x, Wr1, aggr, ihist, h, part1);
    k_bnfin<<<1, 128, 0, stream>>>(part1, g1, be1, ss1);
    k_prepH<<<(N_NODES * 8 + 255) / 256, 256, 0, stream>>>(h, ss1, hn, hhi, hlo);

    // ---- layer 2 ----
    hipMemsetAsync(aggr, 0, (size_t)N_NODES * 64 * sizeof(float), stream);
    k_edge<<<N_EDGES / 64, 256, 0, stream>>>(hhi, hlo, ea, ssrc, sdsts, seid, Wh2, Wl2, bn2, aggr);
    k_combine<<<NB_COMBINE, 256, 0, stream>>>(hn, Wr2, aggr, ihist, h, part2);
    k_bnfin<<<1, 128, 0, stream>>>(part2, g2, be2, ss2);

    // ---- readout (BN-apply fused into pool) ----
    k_bnpool<<<256, 256, 0, stream>>>(h, ss2, batch, gsum);
    k_final<<<NUM_GRAPHS, 64, 0, stream>>>(gsum, gcnt, Wro, bro, (float*)d_out);
}